// Round 16
// baseline (159.349 us; speedup 1.0000x reference)
//
#include <hip/hip_runtime.h>
#include <hip/hip_bf16.h>

// Problem constants (from reference)
#define V 50000
#define D 128
#define B 2048
#define P 20

// Stage-1: x[B][D] = inputs[B][V] @ W_emb[D][V]^T, split-K, stream-reduced
#define BM 32
#define BK 64
#define NSPLIT 16               // 2 splits per XCD; KC uniform
#define KC 3136                 // 49 steps of 64 k, uniform for ALL splits
#define NSTEPS 49
#define VPAD (NSPLIT * KC)      // 50176 (zero-padded fragment-ordered W)
#define NSLICE (VPAD / 32)      // 1568
#define NMT (B / BM)            // 64 m-tiles -> grid 1024 = exactly 4 blocks/CU

typedef float  f32x4  __attribute__((ext_vector_type(4)));
typedef short  bf16x8 __attribute__((ext_vector_type(8)));
typedef unsigned int uint4v __attribute__((ext_vector_type(4)));

__device__ __forceinline__ unsigned int pk2(float a, float b) {
    return (__float_as_uint(b) & 0xFFFF0000u) | (__float_as_uint(a) >> 16);
}
__device__ __forceinline__ unsigned short f2bf(float f) {
    unsigned int u = __float_as_uint(f);
    return (unsigned short)((u + 0x7FFFu + ((u >> 16) & 1u)) >> 16);
}
__device__ __forceinline__ bf16x8 pack8(f32x4 lo, f32x4 hi) {
    union { uint4v u; bf16x8 h; } r;
    r.u.x = pk2(lo[0], lo[1]); r.u.y = pk2(lo[2], lo[3]);
    r.u.z = pk2(hi[0], hi[1]); r.u.w = pk2(hi[2], hi[3]);
    return r.h;
}

// ---- pre-pass: W_emb fp32 [D][V] -> WTF, MFMA-fragment-ordered bf16 (zero-pad to VPAD).
// WTF: slice ks5 (32 k), coltile n (16 cols), lane l: off = ks5*8192 + n*1024 + l*16.
__global__ __launch_bounds__(256)
void w2v_wcast(const float* __restrict__ Wemb, unsigned short* __restrict__ WTF) {
    __shared__ unsigned short L[128 * 128];        // 32 KB [d][128 k] swizzled chunks
    const int bk = blockIdx.x;                     // 0..391: k-window [bk*128, +128)
    const int t  = threadIdx.x;
    const int d = t >> 1, h = t & 1;
    const float* src = Wemb + (size_t)d * V + bk * 128 + h * 64;
#pragma unroll
    for (int j = 0; j < 8; ++j) {
        const int kg = bk * 128 + h * 64 + j * 8;
        f32x4 v0 = {0,0,0,0}, v1 = {0,0,0,0};
        if (kg + 8 <= V) {                         // V%8==0 -> full or pad
            const f32x4* p = reinterpret_cast<const f32x4*>(src + j * 8);
            v0 = p[0]; v1 = p[1];
        }
        uint4v u;
        u.x = pk2(v0[0], v0[1]); u.y = pk2(v0[2], v0[3]);
        u.z = pk2(v1[0], v1[1]); u.w = pk2(v1[2], v1[3]);
        const int c8 = h * 8 + j;
        *reinterpret_cast<uint4v*>((char*)L + d * 256 + ((c8 ^ (d & 15)) << 4)) = u;
    }
    __syncthreads();
    const int w = t >> 6, l = t & 63;
    const int kg4 = l >> 4, fr = l & 15;
#pragma unroll
    for (int sl = 0; sl < 4; ++sl)
#pragma unroll
        for (int j2 = 0; j2 < 2; ++j2) {
            const int n  = w + j2 * 4;
            const int dd = n * 16 + fr;
            const int c8 = sl * 4 + kg4;
            uint4v u = *reinterpret_cast<const uint4v*>(
                (char*)L + dd * 256 + ((c8 ^ (dd & 15)) << 4));
            *reinterpret_cast<uint4v*>(
                (char*)WTF + ((size_t)(bk * 4 + sl) * 8 + n) * 1024 + l * 16) = u;
        }
}

// ---- stage 1: stream-reduced split-K GEMM (R15 phase discipline, 4 blocks/CU) ----
// 1024 blocks x 32 rows = 32k row-streams, each advancing sequentially (+256 B/step).
// LDS 40 KB: A dbuf 2x4 KB frag-major + W dbuf 2x16 KB frag-major (both conflict-free).
// Per step: writeLDS ; lgkm-barrier ; loads(t+1) ; 8 MFMA/wave ; lgkm-barrier.
template<int FAST>
__global__ __launch_bounds__(256, 4)
void w2v_gemm(const float* __restrict__ Ain, const void* __restrict__ Wsrc,
              void* __restrict__ part) {
    __shared__ char smem[40960];           // A: [0,8K) 2x4K; W: [8K,40K) 2x16K

    const int i   = blockIdx.x;            // 0..1023
    const int xcd = i & 7;
    const int j   = i >> 3;                // 0..127
    const int s   = xcd * 2 + (j >> 6);    // 0..15 (2 splits per XCD, co-resident)
    const int mt  = j & 63;
    const int m0  = mt * BM;
    const int k0  = s * KC;

    const int tid  = threadIdx.x;
    const int lane = tid & 63;
    const int wid  = tid >> 6;             // wave -> coltiles {wid*2, wid*2+1}
    const int fr   = lane & 15;
    const int kg4  = lane >> 4;

    f32x4 acc[2][2] = {};                  // [m-frag][n-frag]

    // A staging: thread = (row tid>>3, chunk c8 = tid&7): 32 B per thread per step
    const int arow = tid >> 3;             // 0..31
    const int c8   = tid & 7;
    const float* aSrc = Ain + (size_t)(m0 + arow) * V + c8 * 8;
    // frag-major A dst: tile (kc=c8>>2, mf=row>>4), slot = kg4*16 + rowin
    const unsigned dstA = (unsigned)(((c8 >> 2) * 2 + (arow >> 4)) * 1024
                          + ((c8 & 3) * 16 + (arow & 15)) * 16);

    const unsigned short* WT = (const unsigned short*)Wsrc;   // FAST: WTF
    const float*          Wf = (const float*)Wsrc;            // !FAST: fp32 [D][V]

    f32x4 aR[2];
    uint4v wR[4];

    auto loadregs = [&](int ks) {
        const int kg = ks + c8 * 8;
        if (kg + 8 <= V) {                 // 8-granular exact (both multiples of 8)
            const f32x4* ap = reinterpret_cast<const f32x4*>(aSrc + ks);
            aR[0] = ap[0]; aR[1] = ap[1];
        } else {
            aR[0] = f32x4{0.f, 0.f, 0.f, 0.f};
            aR[1] = f32x4{0.f, 0.f, 0.f, 0.f};
        }
        if (FAST) {                        // contiguous 16 KB window of WTF
            const char* wb = (const char*)WT + (size_t)(ks >> 5) * 8192 + tid * 16;
#pragma unroll
            for (int it = 0; it < 4; ++it)
                wR[it] = *reinterpret_cast<const uint4v*>(wb + it * 4096);
        }
    };
    auto writeLDS = [&](int cur) {
        uint4v ua;
        ua.x = pk2(aR[0][0], aR[0][1]); ua.y = pk2(aR[0][2], aR[0][3]);
        ua.z = pk2(aR[1][0], aR[1][1]); ua.w = pk2(aR[1][2], aR[1][3]);
        *reinterpret_cast<uint4v*>(smem + cur * 4096 + dstA) = ua;
        if (FAST) {
#pragma unroll
            for (int it = 0; it < 4; ++it)
                *reinterpret_cast<uint4v*>(smem + 8192 + cur * 16384 + tid * 16 + it * 4096) = wR[it];
        }
    };

    if (FAST) {
        loadregs(k0);
        for (int t = 0; t < NSTEPS; ++t) {
            const int cur = t & 1;
            writeLDS(cur);
            asm volatile("s_waitcnt lgkmcnt(0)" ::: "memory");
            __builtin_amdgcn_s_barrier();
            if (t + 1 < NSTEPS) loadregs(k0 + (t + 1) * 64);   // stays in flight
            const char* Ab = smem + cur * 4096;
            const char* Wb2 = smem + 8192 + cur * 16384;
#pragma unroll
            for (int kc = 0; kc < 2; ++kc) {
                bf16x8 af[2];
#pragma unroll
                for (int mf = 0; mf < 2; ++mf)
                    af[mf] = *reinterpret_cast<const bf16x8*>(
                        Ab + (kc * 2 + mf) * 1024 + lane * 16);
#pragma unroll
                for (int nn = 0; nn < 2; ++nn) {
                    const bf16x8 wf = *reinterpret_cast<const bf16x8*>(
                        Wb2 + (kc * 8 + wid * 2 + nn) * 1024 + lane * 16);
                    acc[0][nn] = __builtin_amdgcn_mfma_f32_16x16x32_bf16(af[0], wf, acc[0][nn], 0, 0, 0);
                    acc[1][nn] = __builtin_amdgcn_mfma_f32_16x16x32_bf16(af[1], wf, acc[1][nn], 0, 0, 0);
                }
            }
            asm volatile("s_waitcnt lgkmcnt(0)" ::: "memory");
            __builtin_amdgcn_s_barrier();
        }
    } else {
        for (int t = 0; t < NSTEPS; ++t) {
            const int ks = k0 + t * 64;
            loadregs(ks);
            writeLDS(0);
            __syncthreads();
#pragma unroll
            for (int kc = 0; kc < 2; ++kc) {
                bf16x8 af[2];
#pragma unroll
                for (int mf = 0; mf < 2; ++mf)
                    af[mf] = *reinterpret_cast<const bf16x8*>(
                        smem + (kc * 2 + mf) * 1024 + lane * 16);
#pragma unroll
                for (int nn = 0; nn < 2; ++nn) {
                    const int dd = (wid * 2 + nn) * 16 + fr;
                    const int kg = ks + kc * 32 + kg4 * 8;
                    f32x4 lo = {0,0,0,0}, hi = {0,0,0,0};
                    if (kg + 8 <= V) {
                        const f32x4* p = reinterpret_cast<const f32x4*>(Wf + (size_t)dd * V + kg);
                        lo = p[0]; hi = p[1];
                    }
                    const bf16x8 wf = pack8(lo, hi);
                    acc[0][nn] = __builtin_amdgcn_mfma_f32_16x16x32_bf16(af[0], wf, acc[0][nn], 0, 0, 0);
                    acc[1][nn] = __builtin_amdgcn_mfma_f32_16x16x32_bf16(af[1], wf, acc[1][nn], 0, 0, 0);
                }
            }
            __syncthreads();
        }
    }

    // ---- epilogue (C/D layout: col = lane&15, row = kg4*4 + jj) ----
    if (!FAST) {
        float* outp = (float*)part;        // fp32 [B][D], atomic accumulate
#pragma unroll
        for (int mf = 0; mf < 2; ++mf) {
            const int r0 = m0 + mf * 16 + kg4 * 4;
#pragma unroll
            for (int nn = 0; nn < 2; ++nn) {
                const int c = (wid * 2 + nn) * 16 + fr;
#pragma unroll
                for (int jj = 0; jj < 4; ++jj)
                    atomicAdd(&outp[(size_t)(r0 + jj) * D + c], acc[mf][nn][jj]);
            }
        }
        return;
    }
    asm volatile("s_waitcnt lgkmcnt(0)" ::: "memory");
    __builtin_amdgcn_s_barrier();
    unsigned short* Cs = (unsigned short*)smem;   // [32][128] bf16 = 8 KB
#pragma unroll
    for (int mf = 0; mf < 2; ++mf) {
        const int r0 = mf * 16 + kg4 * 4;
#pragma unroll
        for (int nn = 0; nn < 2; ++nn) {
            const int c = (wid * 2 + nn) * 16 + fr;
#pragma unroll
            for (int jj = 0; jj < 4; ++jj)
                Cs[(r0 + jj) * 128 + c] = f2bf(acc[mf][nn][jj]);
        }
    }
    __syncthreads();
    char* dstb = (char*)part + ((size_t)s * B + m0) * (D * 2);   // [s][b][d] bf16
#pragma unroll
    for (int it = 0; it < 2; ++it) {
        const int off = (it * 256 + tid) * 16;                   // 8 KB coalesced
        *reinterpret_cast<uint4v*>(dstb + off) =
            *reinterpret_cast<const uint4v*>(smem + off);
    }
}

// ---- stage 2: reduce splits + gathered cls dots + BCE + mean ----
__global__ __launch_bounds__(256)
void w2v_loss(const void* __restrict__ part, int part_bf16,
              const float* __restrict__ Wcls, const int* __restrict__ pathIdx,
              const float* __restrict__ codes, const float* __restrict__ mask,
              float* __restrict__ out) {
    const int lane = threadIdx.x & 63;
    const int wid  = threadIdx.x >> 6;
    const int b    = blockIdx.x * 4 + wid;     // one wave per sample

    float x0 = 0.f, x1 = 0.f;                  // x[b][2*lane], x[b][2*lane+1]
    if (part_bf16) {
        const unsigned* pb = (const unsigned*)part;   // 64 u32 per [s][b] row
#pragma unroll
        for (int s = 0; s < NSPLIT; ++s) {
            unsigned u = pb[((size_t)s * B + b) * 64 + lane];
            x0 += __uint_as_float(u << 16);
            x1 += __uint_as_float(u & 0xFFFF0000u);
        }
    } else {
        const float* pf = (const float*)part;         // [B][D] fp32, pre-reduced
        const float2 v = *reinterpret_cast<const float2*>(&pf[(size_t)b * D + lane * 2]);
        x0 = v.x; x1 = v.y;
    }

    float lsum = 0.f, msum = 0.f;
#pragma unroll
    for (int p = 0; p < P; ++p) {
        int node = pathIdx[b * P + p];
        const float2 w = *reinterpret_cast<const float2*>(&Wcls[(size_t)node * D + lane * 2]);
        float d = x0 * w.x + x1 * w.y;
#pragma unroll
        for (int off = 1; off < 64; off <<= 1)
            d += __shfl_xor(d, off, 64);
        float t  = codes[b * P + p];
        float mm = mask[b * P + p];
        float loss = fmaxf(d, 0.f) - d * t + log1pf(__expf(-fabsf(d)));
        lsum += loss * mm;
        msum += mm;
    }
    float per = (msum > 0.f) ? (lsum / msum) : 0.f;

    __shared__ float wsum[4];
    if (lane == 0) wsum[wid] = per;
    __syncthreads();
    if (threadIdx.x == 0) {
        float ssum = wsum[0] + wsum[1] + wsum[2] + wsum[3];
        atomicAdd(out, ssum * (1.0f / (float)B));
    }
}

extern "C" void kernel_launch(void* const* d_in, const int* in_sizes, int n_in,
                              void* d_out, int out_size, void* d_ws, size_t ws_size,
                              hipStream_t stream) {
    const float* inputs = (const float*)d_in[0];   // [B,V]
    const float* W_emb  = (const float*)d_in[1];   // [D,V]
    const float* W_cls  = (const float*)d_in[2];   // [V,D]
    const int*   path   = (const int*)  d_in[3];   // [B,P]
    const float* codes  = (const float*)d_in[4];   // [B,P]
    const float* mask   = (const float*)d_in[5];   // [B,P]
    float* out = (float*)d_out;

    hipMemsetAsync(d_out, 0, sizeof(float), stream);

    const size_t wtf_bytes  = (size_t)NSLICE * 8192;                  // ~12.85 MB
    const size_t part_off   = (wtf_bytes + 255) & ~(size_t)255;
    const size_t part_bytes = (size_t)NSPLIT * B * D * 2;             // ~8.4 MB

    if (ws_size >= part_off + part_bytes) {
        unsigned short* WTF = (unsigned short*)d_ws;
        char* partp = (char*)d_ws + part_off;
        w2v_wcast<<<dim3(VPAD / 128), dim3(256), 0, stream>>>(W_emb, WTF);
        w2v_gemm<1><<<dim3(NMT * NSPLIT), dim3(256), 0, stream>>>(inputs, WTF, partp);
        w2v_loss<<<dim3(B / 4), dim3(256), 0, stream>>>(partp, 1, W_cls, path, codes, mask, out);
    } else {
        hipMemsetAsync(d_ws, 0, (size_t)B * D * sizeof(float), stream);
        w2v_gemm<0><<<dim3(NMT * NSPLIT), dim3(256), 0, stream>>>(inputs, W_emb, d_ws);
        w2v_loss<<<dim3(B / 4), dim3(256), 0, stream>>>(d_ws, 0, W_cls, path, codes, mask, out);
    }
}

// Round 17
// 142.540 us; speedup vs baseline: 1.1179x; 1.1179x over previous
//
#include <hip/hip_runtime.h>
#include <hip/hip_bf16.h>

// Problem constants (from reference)
#define V 50000
#define D 128
#define B 2048
#define P 20

// Stage-1: x[B][D] = inputs[B][V] @ W_emb[D][V]^T, split-K (R8 structure + WTF W)
#define BM 128
#define BK 64
#define NSPLIT 48               // 8 XCDs x 6 splits; grid 16*48 = 768 = exactly 3 blocks/CU
#define KC 1056                 // 33 slices of 32 k per split; 17 steps of 64 (s=47: 6)
#define VPAD (NSPLIT * KC)      // 50688 (zero-padded fragment-ordered W)
#define NSLICE (VPAD / 32)      // 1584
#define NMT (B / BM)            // 16

typedef float  f32x4  __attribute__((ext_vector_type(4)));
typedef short  bf16x8 __attribute__((ext_vector_type(8)));
typedef unsigned int uint4v __attribute__((ext_vector_type(4)));

__device__ __forceinline__ unsigned int pk2(float a, float b) {
    return (__float_as_uint(b) & 0xFFFF0000u) | (__float_as_uint(a) >> 16);
}
__device__ __forceinline__ unsigned short f2bf(float f) {
    unsigned int u = __float_as_uint(f);
    return (unsigned short)((u + 0x7FFFu + ((u >> 16) & 1u)) >> 16);
}
__device__ __forceinline__ bf16x8 pack8(f32x4 lo, f32x4 hi) {
    union { uint4v u; bf16x8 h; } r;
    r.u.x = pk2(lo[0], lo[1]); r.u.y = pk2(lo[2], lo[3]);
    r.u.z = pk2(hi[0], hi[1]); r.u.w = pk2(hi[2], hi[3]);
    return r.h;
}

// ---- pre-pass: W_emb fp32 [D][V] -> WTF, MFMA-fragment-ordered bf16 (zero-pad to VPAD).
// WTF: slice ks5 (32 k), coltile n (16 cols), lane l: off = ks5*8192 + n*1024 + l*16.
__global__ __launch_bounds__(256)
void w2v_wcast(const float* __restrict__ Wemb, unsigned short* __restrict__ WTF) {
    __shared__ unsigned short L[128 * 128];        // 32 KB [d][128 k] swizzled chunks
    const int bk = blockIdx.x;                     // 0..395: k-window [bk*128, +128)
    const int t  = threadIdx.x;
    const int d = t >> 1, h = t & 1;
    const float* src = Wemb + (size_t)d * V + bk * 128 + h * 64;
#pragma unroll
    for (int j = 0; j < 8; ++j) {
        const int kg = bk * 128 + h * 64 + j * 8;
        f32x4 v0 = {0,0,0,0}, v1 = {0,0,0,0};
        if (kg + 8 <= V) {                         // V%8==0 -> full or pad
            const f32x4* p = reinterpret_cast<const f32x4*>(src + j * 8);
            v0 = p[0]; v1 = p[1];
        }
        uint4v u;
        u.x = pk2(v0[0], v0[1]); u.y = pk2(v0[2], v0[3]);
        u.z = pk2(v1[0], v1[1]); u.w = pk2(v1[2], v1[3]);
        const int c8 = h * 8 + j;
        *reinterpret_cast<uint4v*>((char*)L + d * 256 + ((c8 ^ (d & 15)) << 4)) = u;
    }
    __syncthreads();
    const int w = t >> 6, l = t & 63;
    const int kg4 = l >> 4, fr = l & 15;
#pragma unroll
    for (int sl = 0; sl < 4; ++sl)
#pragma unroll
        for (int j2 = 0; j2 < 2; ++j2) {
            const int n  = w + j2 * 4;
            const int dd = n * 16 + fr;
            const int c8 = sl * 4 + kg4;
            uint4v u = *reinterpret_cast<const uint4v*>(
                (char*)L + dd * 256 + ((c8 ^ (dd & 15)) << 4));
            *reinterpret_cast<uint4v*>(
                (char*)WTF + ((size_t)(bk * 4 + sl) * 8 + n) * 1024 + l * 16) = u;
        }
}

// ---- stage 1: R8 issue-early reg pipeline + W from WTF (contiguous, conflict-free) ----
// Per step: writeLDS(regs[t]) ; lgkm-barrier ; issue loads(t+1) ; 32 MFMA ; lgkm-barrier.
// W LDS is fragment-major: stage loads contiguous 16 KB/step, wf reads contiguous 1 KB.
template<int FAST>
__global__ __launch_bounds__(256, 3)
void w2v_gemm(const float* __restrict__ Ain, const void* __restrict__ Wsrc,
              void* __restrict__ part) {
    __shared__ unsigned short Sm[2 * BM * BK];   // 32 KB: As=[0,16K), Ws=[16K,32K)
    char* AsB = (char*)Sm;
    char* WsB = (char*)(Sm + BM * BK);

    const int i   = blockIdx.x;            // 0..767
    const int xcd = i & 7;
    const int q   = i >> 3;                // 0..95
    const int s   = xcd * 6 + (q >> 4);    // 0..47
    const int mt  = q & 15;
    const int m0  = mt * BM;
    const int k0  = s * KC;
    const int k1  = (k0 + KC < V) ? (k0 + KC) : V;   // k1 % 16 == 0 always
    const int nsteps = (k1 - k0 + 63) >> 6;          // 17 (s=47: 6)

    const int tid  = threadIdx.x;
    const int lane = tid & 63;
    const int wid  = tid >> 6;
    const int w32  = wid * 32;
    const int fr   = lane & 15;
    const int kg4  = lane >> 4;

    f32x4 acc[2][8] = {};

    // A staging geometry (R8): row = rbase + it*32, chunk c8 = tid&7 (it-invariant)
    const int rbase = tid >> 3;
    const int c8    = tid & 7;
    const int c8x   = c8 ^ (rbase & 7);
    const float* aBase = Ain + (size_t)(m0 + rbase) * V + c8 * 8;
    const unsigned short* WT = (const unsigned short*)Wsrc;    // FAST: WTF
    const float*          Wf = (const float*)Wsrc;             // !FAST: fp32 [D][V]

    f32x4 aR[8];
    uint4v wR[4];
    f32x4 wRf[8];                          // !FAST staging

    auto loadregs = [&](int ks) {
        const bool ag = (ks + c8 * 8 + 8 <= k1);       // 8-granular (k1%16==0)
#pragma unroll
        for (int it = 0; it < 4; ++it) {
            const float* ap = aBase + (size_t)(it * 32) * V + ks;
            if (ag) {
                aR[it * 2]     = *reinterpret_cast<const f32x4*>(ap);
                aR[it * 2 + 1] = *reinterpret_cast<const f32x4*>(ap + 4);
            } else {
                aR[it * 2] = f32x4{0.f, 0.f, 0.f, 0.f};
                aR[it * 2 + 1] = f32x4{0.f, 0.f, 0.f, 0.f};
            }
        }
        if (FAST) {
            // contiguous 16 KB: WTF[ks5*8192 .. +16384), thread reads tid*16 + it*4096
            const char* wb = (const char*)WT + (size_t)(ks >> 5) * 8192 + tid * 16;
#pragma unroll
            for (int it = 0; it < 4; ++it)
                wR[it] = *reinterpret_cast<const uint4v*>(wb + it * 4096);
        } else {
            const bool wg = (ks + c8 * 8 + 8 <= V);
#pragma unroll
            for (int it = 0; it < 4; ++it) {
                const float* wp = Wf + (size_t)(rbase + it * 32) * V + c8 * 8 + ks;
                if (wg) {
                    wRf[it * 2]     = *reinterpret_cast<const f32x4*>(wp);
                    wRf[it * 2 + 1] = *reinterpret_cast<const f32x4*>(wp + 4);
                } else {
                    wRf[it * 2] = f32x4{0.f, 0.f, 0.f, 0.f};
                    wRf[it * 2 + 1] = f32x4{0.f, 0.f, 0.f, 0.f};
                }
            }
        }
    };

    auto writeLDS = [&]() {
#pragma unroll
        for (int it = 0; it < 4; ++it) {
            // A: R8 swizzled row-major (write residues uniform, 2-way-free)
            const unsigned dstA = (unsigned)((rbase + it * 32) * 128) + (unsigned)(c8x * 16);
            uint4v ua;
            ua.x = pk2(aR[it * 2][0], aR[it * 2][1]);
            ua.y = pk2(aR[it * 2][2], aR[it * 2][3]);
            ua.z = pk2(aR[it * 2 + 1][0], aR[it * 2 + 1][1]);
            ua.w = pk2(aR[it * 2 + 1][2], aR[it * 2 + 1][3]);
            *reinterpret_cast<uint4v*>(AsB + dstA) = ua;
            if (FAST) {
                // W: frag-major, contiguous lane-order (conflict-free)
                *reinterpret_cast<uint4v*>(WsB + tid * 16 + it * 4096) = wR[it];
            } else {
                const int d = rbase + it * 32;     // W row
                const unsigned dstW = (unsigned)(((c8 >> 2) * 8 + (d >> 4)) * 1024
                                     + ((c8 & 3) * 16 + (d & 15)) * 16);
                uint4v uw;
                uw.x = pk2(wRf[it * 2][0], wRf[it * 2][1]);
                uw.y = pk2(wRf[it * 2][2], wRf[it * 2][3]);
                uw.z = pk2(wRf[it * 2 + 1][0], wRf[it * 2 + 1][1]);
                uw.w = pk2(wRf[it * 2 + 1][2], wRf[it * 2 + 1][3]);
                *reinterpret_cast<uint4v*>(WsB + dstW) = uw;
            }
        }
    };

    loadregs(k0);                          // prologue

    for (int t = 0; t < nsteps; ++t) {
        writeLDS();
        asm volatile("s_waitcnt lgkmcnt(0)" ::: "memory");
        __builtin_amdgcn_s_barrier();      // raw: no vmcnt drain
        if (t + 1 < nsteps) loadregs(k0 + (t + 1) * 64);   // stays in flight
#pragma unroll
        for (int kk = 0; kk < BK; kk += 32) {
            const int cbase = (kk >> 3) + kg4;
            bf16x8 af[2];
#pragma unroll
            for (int m = 0; m < 2; ++m) {
                const int r = w32 + m * 16 + fr;
                af[m] = *reinterpret_cast<const bf16x8*>(
                    AsB + r * 128 + ((cbase ^ (r & 7)) << 4));
            }
#pragma unroll
            for (int n = 0; n < 8; ++n) {
                const bf16x8 wf = *reinterpret_cast<const bf16x8*>(
                    WsB + ((kk >> 5) * 8 + n) * 1024 + lane * 16);
                acc[0][n] = __builtin_amdgcn_mfma_f32_16x16x32_bf16(af[0], wf, acc[0][n], 0, 0, 0);
                acc[1][n] = __builtin_amdgcn_mfma_f32_16x16x32_bf16(af[1], wf, acc[1][n], 0, 0, 0);
            }
        }
        asm volatile("s_waitcnt lgkmcnt(0)" ::: "memory");
        __builtin_amdgcn_s_barrier();
    }

    // ---- epilogue (C/D layout: col = lane&15, row = kg4*4 + jj) ----
    if (!FAST) {
        float* outp = (float*)part;        // fp32 [B][D], atomic accumulate
#pragma unroll
        for (int m = 0; m < 2; ++m) {
            const int r0 = m0 + w32 + m * 16 + kg4 * 4;
#pragma unroll
            for (int n = 0; n < 8; ++n) {
                const int c = n * 16 + fr;
#pragma unroll
                for (int jj = 0; jj < 4; ++jj)
                    atomicAdd(&outp[(size_t)(r0 + jj) * D + c], acc[m][n][jj]);
            }
        }
        return;
    }
    unsigned short* Cs = Sm;               // [128][128] bf16 = 32 KB
#pragma unroll
    for (int m = 0; m < 2; ++m) {
        const int r0 = w32 + m * 16 + kg4 * 4;
#pragma unroll
        for (int n = 0; n < 8; ++n) {
            const int c = n * 16 + fr;
#pragma unroll
            for (int jj = 0; jj < 4; ++jj)
                Cs[(r0 + jj) * 128 + c] = f2bf(acc[m][n][jj]);
        }
    }
    __syncthreads();
    char* dstb = (char*)part + ((size_t)s * B + m0) * (D * 2);   // [s][b][d] bf16
#pragma unroll
    for (int it = 0; it < 8; ++it) {
        const int off = (it * 256 + tid) * 16;                   // 32 KB coalesced
        uint4v v = *reinterpret_cast<const uint4v*>((char*)Sm + off);
        *reinterpret_cast<uint4v*>(dstb + off) = v;
    }
}

// ---- stage 2: reduce splits + gathered cls dots + BCE + mean ----
__global__ __launch_bounds__(256)
void w2v_loss(const void* __restrict__ part, int part_bf16,
              const float* __restrict__ Wcls, const int* __restrict__ pathIdx,
              const float* __restrict__ codes, const float* __restrict__ mask,
              float* __restrict__ out) {
    const int lane = threadIdx.x & 63;
    const int wid  = threadIdx.x >> 6;
    const int b    = blockIdx.x * 4 + wid;     // one wave per sample

    float x0 = 0.f, x1 = 0.f;                  // x[b][2*lane], x[b][2*lane+1]
    if (part_bf16) {
        const unsigned* pb = (const unsigned*)part;   // 64 u32 per [s][b] row
#pragma unroll 8
        for (int s = 0; s < NSPLIT; ++s) {
            unsigned u = pb[((size_t)s * B + b) * 64 + lane];
            x0 += __uint_as_float(u << 16);
            x1 += __uint_as_float(u & 0xFFFF0000u);
        }
    } else {
        const float* pf = (const float*)part;         // [B][D] fp32, pre-reduced
        const float2 v = *reinterpret_cast<const float2*>(&pf[(size_t)b * D + lane * 2]);
        x0 = v.x; x1 = v.y;
    }

    float lsum = 0.f, msum = 0.f;
#pragma unroll
    for (int p = 0; p < P; ++p) {
        int node = pathIdx[b * P + p];
        const float2 w = *reinterpret_cast<const float2*>(&Wcls[(size_t)node * D + lane * 2]);
        float d = x0 * w.x + x1 * w.y;
#pragma unroll
        for (int off = 1; off < 64; off <<= 1)
            d += __shfl_xor(d, off, 64);
        float t  = codes[b * P + p];
        float mm = mask[b * P + p];
        float loss = fmaxf(d, 0.f) - d * t + log1pf(__expf(-fabsf(d)));
        lsum += loss * mm;
        msum += mm;
    }
    float per = (msum > 0.f) ? (lsum / msum) : 0.f;

    __shared__ float wsum[4];
    if (lane == 0) wsum[wid] = per;
    __syncthreads();
    if (threadIdx.x == 0) {
        float ssum = wsum[0] + wsum[1] + wsum[2] + wsum[3];
        atomicAdd(out, ssum * (1.0f / (float)B));
    }
}

extern "C" void kernel_launch(void* const* d_in, const int* in_sizes, int n_in,
                              void* d_out, int out_size, void* d_ws, size_t ws_size,
                              hipStream_t stream) {
    const float* inputs = (const float*)d_in[0];   // [B,V]
    const float* W_emb  = (const float*)d_in[1];   // [D,V]
    const float* W_cls  = (const float*)d_in[2];   // [V,D]
    const int*   path   = (const int*)  d_in[3];   // [B,P]
    const float* codes  = (const float*)d_in[4];   // [B,P]
    const float* mask   = (const float*)d_in[5];   // [B,P]
    float* out = (float*)d_out;

    hipMemsetAsync(d_out, 0, sizeof(float), stream);

    const size_t wtf_bytes  = (size_t)NSLICE * 8192;                  // ~13.0 MB
    const size_t part_off   = (wtf_bytes + 255) & ~(size_t)255;
    const size_t part_bytes = (size_t)NSPLIT * B * D * 2;             // ~25.2 MB

    if (ws_size >= part_off + part_bytes) {
        unsigned short* WTF = (unsigned short*)d_ws;
        char* partp = (char*)d_ws + part_off;
        w2v_wcast<<<dim3(VPAD / 128), dim3(256), 0, stream>>>(W_emb, WTF);
        w2v_gemm<1><<<dim3(NMT * NSPLIT), dim3(256), 0, stream>>>(inputs, WTF, partp);
        w2v_loss<<<dim3(B / 4), dim3(256), 0, stream>>>(partp, 1, W_cls, path, codes, mask, out);
    } else {
        hipMemsetAsync(d_ws, 0, (size_t)B * D * sizeof(float), stream);
        w2v_gemm<0><<<dim3(NMT * NSPLIT), dim3(256), 0, stream>>>(inputs, W_emb, d_ws);
        w2v_loss<<<dim3(B / 4), dim3(256), 0, stream>>>(d_ws, 0, W_cls, path, codes, mask, out);
    }
}